// Round 5
// baseline (20.302 us; speedup 1.0000x reference)
//
#include <hip/hip_runtime.h>

// Problem constants: B=128, P=2048, N=256, D=2
constexpr int B   = 128;
constexpr int P   = 2048;
constexpr int N   = 256;
constexpr int TPB = 256;   // 4 waves
constexpr int NPB = 8;     // centers per block (every wave computes all of them)
constexpr int KQ  = 4;     // float4 loads per lane = 8 points/lane
// Each wave owns a disjoint 512-point slice: wave w -> points [w*512, w*512+512)

__device__ __forceinline__ float rdfl(float v) {
    return __int_as_float(__builtin_amdgcn_readfirstlane(__float_as_int(v)));
}

__global__ __launch_bounds__(TPB, 8)   // 64-VGPR budget; est. use ~48
void SLayerRational_43190191128606_kernel(
    const float* __restrict__ batch,      // (B, P, 2)
    const float* __restrict__ not_dummy,  // (B, P)
    const float* __restrict__ centers,    // (N, 2)
    const float* __restrict__ sharpness,  // (N, 2)
    const float* __restrict__ exponent,   // (1,)
    float* __restrict__ out)              // (B, N)
{
    const int b    = blockIdx.x >> 5;          // N/NPB = 32 tiles per batch row
    const int n0   = (blockIdx.x & 31) * NPB;
    const int wave = threadIdx.x >> 6;
    const int lane = threadIdx.x & 63;

    // Wave-uniform center params -> SGPRs (8 centers, shared by all waves)
    float c0[NPB], c1[NPB], a0[NPB], a1[NPB];
#pragma unroll
    for (int c = 0; c < NPB; ++c) {
        c0[c] = rdfl(centers[(n0 + c) * 2 + 0]);
        c1[c] = rdfl(centers[(n0 + c) * 2 + 1]);
        a0[c] = rdfl(fabsf(sharpness[(n0 + c) * 2 + 0]));
        a1[c] = rdfl(fabsf(sharpness[(n0 + c) * 2 + 1]));
    }
    const float e = exponent[0];

    float acc[NPB];
#pragma unroll
    for (int c = 0; c < NPB; ++c) acc[c] = 0.0f;

    if (e == 1.0f) {
        // ---- Fast path: wave-slice register-resident, all indices static ----
        // float4 = 2 points (x0,y0,x1,y1); float2 = 2 weights.
        const float4* bb4 = reinterpret_cast<const float4*>(batch)
                          + (size_t)b * (P / 2) + wave * 256;
        const float2* nd2 = reinterpret_cast<const float2*>(not_dummy)
                          + (size_t)b * (P / 2) + wave * 256;

        float4 xq[KQ];
        float2 wq[KQ];
#pragma unroll
        for (int k = 0; k < KQ; ++k) {
            xq[k] = bb4[k * 64 + lane];
            wq[k] = nd2[k * 64 + lane];
        }

        // Paired reciprocal: 1/ua + 1/ub = (wa*ub + wb*ua) / (ua*ub)
#pragma unroll
        for (int c = 0; c < NPB; ++c) {
#pragma unroll
            for (int k = 0; k < KQ; ++k) {
                const float4 x = xq[k];
                const float2 w = wq[k];
                const float ua = fmaf(fabsf(c0[c] - x.x), a0[c],
                                  fmaf(fabsf(c1[c] - x.y), a1[c], 1.0f));
                const float ub = fmaf(fabsf(c0[c] - x.z), a0[c],
                                  fmaf(fabsf(c1[c] - x.w), a1[c], 1.0f));
                float num = w.x * ub;
                num = fmaf(w.y, ua, num);
                const float den = ua * ub;
                acc[c] = fmaf(num, __builtin_amdgcn_rcpf(den), acc[c]);
            }
        }
    } else {
        // ---- General path: r = w / (1 + s^e); direct loads, no arrays ----
        const float2* bb = reinterpret_cast<const float2*>(batch)
                         + (size_t)b * P + wave * 512;
        const float*  nd = not_dummy + (size_t)b * P + wave * 512;
        for (int it = 0; it < 8; ++it) {
            const int p = it * 64 + lane;
            const float2 x = bb[p];
            const float  w = nd[p];
#pragma unroll
            for (int c = 0; c < NPB; ++c) {
                const float s = fmaf(fabsf(c0[c] - x.x), a0[c],
                                     fabsf(c1[c] - x.y) * a1[c]);
                acc[c] += w / (1.0f + powf(s, e));
            }
        }
    }

    // ---- Folded wave reduction: 8 accs -> 4 regs across 32-lane halves ----
    // lanes<32 carry centers 0..3, lanes>=32 carry centers 4..7
    const bool lo = (lane < 32);
    float r[4];
#pragma unroll
    for (int j = 0; j < 4; ++j) {
        const float m = lo ? acc[j] : acc[j + 4];
        const float o = lo ? acc[j + 4] : acc[j];
        r[j] = m + __shfl_xor(o, 32, 64);
    }
#pragma unroll
    for (int j = 0; j < 4; ++j) {
#pragma unroll
        for (int off = 16; off > 0; off >>= 1)
            r[j] += __shfl_xor(r[j], off, 64);
    }

    // Cross-wave combine: one float4 LDS write per half-wave leader.
    __shared__ float red[4][NPB];
    if ((lane & 31) == 0) {
        float4* dst = reinterpret_cast<float4*>(&red[wave][(lane >> 5) * 4]);
        *dst = make_float4(r[0], r[1], r[2], r[3]);
    }
    __syncthreads();

    if (threadIdx.x < NPB) {
        const int t = threadIdx.x;
        out[b * N + n0 + t] = red[0][t] + red[1][t] + red[2][t] + red[3][t];
    }
}

extern "C" void kernel_launch(void* const* d_in, const int* in_sizes, int n_in,
                              void* d_out, int out_size, void* d_ws, size_t ws_size,
                              hipStream_t stream) {
    const float* batch     = (const float*)d_in[0];
    const float* not_dummy = (const float*)d_in[1];
    const float* centers   = (const float*)d_in[2];
    const float* sharpness = (const float*)d_in[3];
    const float* exponent  = (const float*)d_in[4];
    float* out = (float*)d_out;

    const int blocks = B * (N / NPB);  // 4096
    SLayerRational_43190191128606_kernel<<<blocks, TPB, 0, stream>>>(
        batch, not_dummy, centers, sharpness, exponent, out);
}